// Round 1
// baseline (176.769 us; speedup 1.0000x reference)
//
#include <hip/hip_runtime.h>
#include <math.h>

// Problem constants (from reference): B,F,C,H,W,D
constexpr int B_ = 2, F_ = 2, C_ = 64, H_ = 32, W_ = 104, D_ = 96;
constexpr int HW_ = H_ * W_;             // 3328
constexpr int NPIX = B_ * D_ * H_ * W_;  // 638976 output elements
#define EPSF 1e-7f

// Workspace layout (floats):
//   lfT  [B,F,H,W,C]  channel-last lookup feats
//   curT [B,H,W,C]    channel-last current feats
//   P    [B,F,12]     (K @ pose)[:3,:]
//   valid[B,F]
constexpr size_t LFT_OFF  = 0;
constexpr size_t CURT_OFF = LFT_OFF + (size_t)B_ * F_ * H_ * W_ * C_;   // 851968
constexpr size_t P_OFF    = CURT_OFF + (size_t)B_ * H_ * W_ * C_;       // +425984
constexpr size_t VALID_OFF= P_OFF + (size_t)B_ * F_ * 12;
// total floats = 1,278,004  (~5.1 MB) — fits typical ws

// ---------------------------------------------------------------------------
// Tiny prep: P = (K @ pose)[:3,:], valid = (sum(pose) != 0)
// FMA chain order matches XLA dot accumulation (sequential over j).
__global__ void prep_kernel(const float* __restrict__ poses,
                            const float* __restrict__ K,
                            float* __restrict__ ws) {
    int tid = threadIdx.x;
    if (tid >= B_ * F_) return;
    int b = tid / F_;
    const float* Kb   = K + (size_t)b * 16;
    const float* pose = poses + (size_t)tid * 16;
    float* P = ws + P_OFF + (size_t)tid * 12;
    for (int i = 0; i < 3; ++i) {
        for (int k = 0; k < 4; ++k) {
            float acc = __fmul_rn(Kb[i*4+0], pose[0*4+k]);
            acc = __fmaf_rn(Kb[i*4+1], pose[1*4+k], acc);
            acc = __fmaf_rn(Kb[i*4+2], pose[2*4+k], acc);
            acc = __fmaf_rn(Kb[i*4+3], pose[3*4+k], acc);
            P[i*4+k] = acc;
        }
    }
    float s = 0.f;
    for (int j = 0; j < 16; ++j) s += pose[j];
    ws[VALID_OFF + tid] = (s != 0.f) ? 1.0f : 0.0f;
}

// ---------------------------------------------------------------------------
// LDS-tiled transpose of a [NCOL, N] slice to [N, NCOL]; blockIdx.z = slice.
template<int NCOL>
__global__ void transpose_cn(const float* __restrict__ in,
                             float* __restrict__ out, int N) {
    __shared__ float tile[32][33];
    int n0 = blockIdx.x * 32;
    int c0 = blockIdx.y * 32;
    const float* inS = in  + (size_t)blockIdx.z * NCOL * N;
    float*      outS = out + (size_t)blockIdx.z * NCOL * N;
    int tx = threadIdx.x, ty = threadIdx.y;
    #pragma unroll
    for (int k = 0; k < 32; k += 8) {
        int c = c0 + ty + k, n = n0 + tx;
        if (c < NCOL && n < N) tile[ty + k][tx] = inS[(size_t)c * N + n];
    }
    __syncthreads();
    #pragma unroll
    for (int k = 0; k < 32; k += 8) {
        int n = n0 + ty + k, c = c0 + tx;
        if (n < N && c < NCOL) outS[(size_t)n * NCOL + c] = tile[tx][ty + k];
    }
}

// ---------------------------------------------------------------------------
// Main cost-volume kernel. 16 lanes per output pixel, each lane = 4 channels.
__global__ __launch_bounds__(256) void cost_kernel(
        const float* __restrict__ invK,
        const float* __restrict__ depth_bins,
        const float* __restrict__ ws,
        float* __restrict__ out) {
    int t    = threadIdx.x;
    int lane = t & 15;                       // channel group within pixel
    int p    = blockIdx.x * 16 + (t >> 4);   // flat output index = ((b*D+d)*H+y)*W+x
    if (p >= NPIX) return;
    int x = p % W_;
    int r = p / W_;
    int y = r % H_;  r /= H_;
    int d = r % D_;
    int b = r / D_;

    const float* lfT    = ws + LFT_OFF;
    const float* curT   = ws + CURT_OFF;
    const float* Pall   = ws + P_OFF;
    const float* validp = ws + VALID_OFF;

    float depth = depth_bins[d];
    const float* iK = invK + (size_t)b * 16;
    float xf = (float)x, yf = (float)y;
    // cam = invK[:3,:3] @ [x,y,1]  (sequential FMA chain = XLA dot order)
    float cam0 = __fmul_rn(iK[0], xf); cam0 = __fmaf_rn(iK[1], yf, cam0); cam0 = __fmaf_rn(iK[2],  1.0f, cam0);
    float cam1 = __fmul_rn(iK[4], xf); cam1 = __fmaf_rn(iK[5], yf, cam1); cam1 = __fmaf_rn(iK[6],  1.0f, cam1);
    float cam2 = __fmul_rn(iK[8], xf); cam2 = __fmaf_rn(iK[9], yf, cam2); cam2 = __fmaf_rn(iK[10], 1.0f, cam2);
    float p0 = __fmul_rn(depth, cam0);
    float p1 = __fmul_rn(depth, cam1);
    float p2 = __fmul_rn(depth, cam2);

    bool interior = (x >= 2) && (x <= W_ - 3) && (y >= 2) && (y <= H_ - 3);

    const float4 cv = *(const float4*)(curT + ((size_t)(b * H_ + y) * W_ + x) * C_ + lane * 4);

    float costsum = 0.f, counts = 0.f;
    #pragma unroll
    for (int f = 0; f < F_; ++f) {
        const float* Pm = Pall + (size_t)(b * F_ + f) * 12;
        float c0 = __fmul_rn(Pm[0], p0); c0 = __fmaf_rn(Pm[1], p1, c0); c0 = __fmaf_rn(Pm[2],  p2, c0); c0 = __fmaf_rn(Pm[3],  1.0f, c0);
        float c1 = __fmul_rn(Pm[4], p0); c1 = __fmaf_rn(Pm[5], p1, c1); c1 = __fmaf_rn(Pm[6],  p2, c1); c1 = __fmaf_rn(Pm[7],  1.0f, c1);
        float c2 = __fmul_rn(Pm[8], p0); c2 = __fmaf_rn(Pm[9], p1, c2); c2 = __fmaf_rn(Pm[10], p2, c2); c2 = __fmaf_rn(Pm[11], 1.0f, c2);
        float denom = __fadd_rn(c2, EPSF);
        float gx = c0 / denom;          // IEEE div, matches XLA
        float gy = c1 / denom;
        float diff = 0.f;
        // edge_mask: under it all 4 bilinear corners are in-bounds -> no clamping needed
        bool m = interior && (gx >= 2.0f) && (gx <= (float)(W_ - 2))
                          && (gy >= 2.0f) && (gy <= (float)(H_ - 2));
        if (m) {
            float x0f = floorf(gx), y0f = floorf(gy);
            int   x0  = (int)x0f,   y0  = (int)y0f;
            float wx1 = gx - x0f, wy1 = gy - y0f;
            float wx0 = 1.f - wx1, wy0 = 1.f - wy1;
            float w00 = wy0 * wx0, w01 = wy0 * wx1, w10 = wy1 * wx0, w11 = wy1 * wx1;
            const float* bp = lfT + (((size_t)(b * F_ + f) * H_ + y0) * W_ + x0) * C_ + lane * 4;
            float4 v00 = *(const float4*)(bp);
            float4 v01 = *(const float4*)(bp + C_);
            float4 v10 = *(const float4*)(bp + (size_t)W_ * C_);
            float4 v11 = *(const float4*)(bp + (size_t)W_ * C_ + C_);
            float s;
            s  = fabsf(v00.x*w00 + v01.x*w01 + v10.x*w10 + v11.x*w11 - cv.x);
            s += fabsf(v00.y*w00 + v01.y*w01 + v10.y*w10 + v11.y*w11 - cv.y);
            s += fabsf(v00.z*w00 + v01.z*w01 + v10.z*w10 + v11.z*w11 - cv.z);
            s += fabsf(v00.w*w00 + v01.w*w01 + v10.w*w10 + v11.w*w11 - cv.w);
            // reduce channel sum across the 16-lane group (mask is group-uniform)
            s += __shfl_xor(s, 1);
            s += __shfl_xor(s, 2);
            s += __shfl_xor(s, 4);
            s += __shfl_xor(s, 8);
            diff = __fmul_rn(s, 1.0f / 64.0f) * validp[b * F_ + f];
        }
        costsum += diff;
        counts  += (diff > 0.f) ? 1.0f : 0.0f;
    }
    float cost = costsum / __fadd_rn(counts, EPSF);
    if (lane == 0) out[p] = cost;
}

// ---------------------------------------------------------------------------
// missing = (cost == 0) -> replace with max over D, in-place on d_out.
__global__ void fix_missing(float* __restrict__ out) {
    int tid = blockIdx.x * blockDim.x + threadIdx.x;
    if (tid >= B_ * HW_) return;
    int b  = tid / HW_;
    int yx = tid % HW_;
    float* base = out + (size_t)b * D_ * HW_ + yx;
    float cmax = -INFINITY;
    for (int d = 0; d < D_; ++d) cmax = fmaxf(cmax, base[(size_t)d * HW_]);
    for (int d = 0; d < D_; ++d) {
        if (base[(size_t)d * HW_] == 0.0f) base[(size_t)d * HW_] = cmax;
    }
}

// ---------------------------------------------------------------------------
extern "C" void kernel_launch(void* const* d_in, const int* in_sizes, int n_in,
                              void* d_out, int out_size, void* d_ws, size_t ws_size,
                              hipStream_t stream) {
    const float* cur        = (const float*)d_in[0];  // [B,C,H,W]
    const float* lf         = (const float*)d_in[1];  // [B,F,C,H,W]
    const float* poses      = (const float*)d_in[2];  // [B,F,4,4]
    const float* K          = (const float*)d_in[3];  // [B,4,4]
    const float* invK       = (const float*)d_in[4];  // [B,4,4]
    const float* depth_bins = (const float*)d_in[5];  // [D]
    float* out = (float*)d_out;
    float* ws  = (float*)d_ws;

    prep_kernel<<<1, 64, 0, stream>>>(poses, K, ws);

    dim3 tb(32, 8);
    // lookup_feats: B*F slices of [C, HW] -> [HW, C]
    transpose_cn<C_><<<dim3(HW_ / 32, C_ / 32, B_ * F_), tb, 0, stream>>>(lf, ws + LFT_OFF, HW_);
    // current_feats: B slices of [C, HW] -> [HW, C]
    transpose_cn<C_><<<dim3(HW_ / 32, C_ / 32, B_), tb, 0, stream>>>(cur, ws + CURT_OFF, HW_);

    cost_kernel<<<NPIX / 16, 256, 0, stream>>>(invK, depth_bins, ws, out);

    fix_missing<<<(B_ * HW_ + 255) / 256, 256, 0, stream>>>(out);
}

// Round 2
// 126.018 us; speedup vs baseline: 1.4027x; 1.4027x over previous
//
#include <hip/hip_runtime.h>
#include <math.h>

// Problem constants: B,F,C,H,W,D
constexpr int B_ = 2, F_ = 2, C_ = 64, H_ = 32, W_ = 104, D_ = 96;
constexpr int HW_ = H_ * W_;             // 3328
constexpr int NPIX = B_ * D_ * H_ * W_;  // 638976 output elements
constexpr int NREC = B_ * F_ * D_ * H_ * W_;  // 1277952 projection records
#define EPSF 1e-7f

// Workspace layout (floats):
//   lfT  [B,F,H,W,C]   channel-last lookup feats
//   curT [B,H,W,C]     channel-last current feats
//   gxy  [B,F,D,H,W]x2 projected coords (float2); masked -> (2.0, -1.0)
constexpr size_t LFT_OFF  = 0;
constexpr size_t CURT_OFF = LFT_OFF + (size_t)B_ * F_ * H_ * W_ * C_;   // 851968
constexpr size_t GXY_OFF  = CURT_OFF + (size_t)B_ * H_ * W_ * C_;       // 1277952
// total floats = 1277952 + 2*1277952 = 3,833,856  (~15.3 MB ws)

constexpr int NT_BLKS = (HW_ / 32) * (C_ / 32) * (B_ * F_ + B_);  // 104*2*6 = 1248
constexpr int PROJ_BLKS = NREC / 256;                              // 4992
constexpr int DCH = 8;                                             // d-chunk per sampling block

// ---------------------------------------------------------------------------
// Fused kernel 1: blocks [0,NT_BLKS) do channel-last transposes;
// blocks [NT_BLKS, ...) compute projections (independent work, no ordering).
__global__ __launch_bounds__(256) void prep_fused(
        const float* __restrict__ cur, const float* __restrict__ lf,
        const float* __restrict__ poses, const float* __restrict__ K,
        const float* __restrict__ invK, const float* __restrict__ depth_bins,
        float* __restrict__ ws) {
    int bid = blockIdx.x;
    if (bid < NT_BLKS) {
        // ---- transpose [C, HW] -> [HW, C] for 6 slices (4 lf + 2 cur) ----
        __shared__ float tile[32][33];
        int slice = bid / 208;            // 208 = 104 n-blocks * 2 c-blocks
        int rem   = bid % 208;
        int nb = rem % 104, cb = rem / 104;
        const float* inS;
        float* outS;
        if (slice < B_ * F_) {
            inS  = lf + (size_t)slice * C_ * HW_;
            outS = ws + LFT_OFF + (size_t)slice * HW_ * C_;
        } else {
            int s2 = slice - B_ * F_;
            inS  = cur + (size_t)s2 * C_ * HW_;
            outS = ws + CURT_OFF + (size_t)s2 * HW_ * C_;
        }
        int t = threadIdx.x;
        int tx = t & 31, ty = t >> 5;
        int n0 = nb * 32, c0 = cb * 32;
        #pragma unroll
        for (int k = 0; k < 32; k += 8)
            tile[ty + k][tx] = inS[(size_t)(c0 + ty + k) * HW_ + n0 + tx];
        __syncthreads();
        #pragma unroll
        for (int k = 0; k < 32; k += 8)
            outS[(size_t)(n0 + ty + k) * C_ + c0 + tx] = tile[tx][ty + k];
        return;
    }
    // ---- projection: one thread per (b,f,d,y,x) ----
    int tid = (bid - NT_BLKS) * 256 + threadIdx.x;   // < NREC exactly
    int x = tid % W_;
    int r = tid / W_;
    int y = r % H_;  r /= H_;
    int d = r % D_;  r /= D_;
    int f = r % F_;
    int b = r / F_;

    const float* Kb   = K + (size_t)b * 16;
    const float* pose = poses + (size_t)(b * F_ + f) * 16;
    // P = (K @ pose)[:3,:], sequential FMA chain (XLA dot order, same as R1)
    float P[12];
    #pragma unroll
    for (int i = 0; i < 3; ++i) {
        #pragma unroll
        for (int k = 0; k < 4; ++k) {
            float acc = __fmul_rn(Kb[i*4+0], pose[0*4+k]);
            acc = __fmaf_rn(Kb[i*4+1], pose[1*4+k], acc);
            acc = __fmaf_rn(Kb[i*4+2], pose[2*4+k], acc);
            acc = __fmaf_rn(Kb[i*4+3], pose[3*4+k], acc);
            P[i*4+k] = acc;
        }
    }
    float vs = 0.f;
    #pragma unroll
    for (int j = 0; j < 16; ++j) vs += pose[j];
    bool valid = (vs != 0.f);

    const float* iK = invK + (size_t)b * 16;
    float xf = (float)x, yf = (float)y;
    float cam0 = __fmul_rn(iK[0], xf); cam0 = __fmaf_rn(iK[1], yf, cam0); cam0 = __fmaf_rn(iK[2],  1.0f, cam0);
    float cam1 = __fmul_rn(iK[4], xf); cam1 = __fmaf_rn(iK[5], yf, cam1); cam1 = __fmaf_rn(iK[6],  1.0f, cam1);
    float cam2 = __fmul_rn(iK[8], xf); cam2 = __fmaf_rn(iK[9], yf, cam2); cam2 = __fmaf_rn(iK[10], 1.0f, cam2);
    float depth = depth_bins[d];
    float p0 = __fmul_rn(depth, cam0);
    float p1 = __fmul_rn(depth, cam1);
    float p2 = __fmul_rn(depth, cam2);

    float c0 = __fmul_rn(P[0], p0); c0 = __fmaf_rn(P[1], p1, c0); c0 = __fmaf_rn(P[2],  p2, c0); c0 = __fmaf_rn(P[3],  1.0f, c0);
    float c1 = __fmul_rn(P[4], p0); c1 = __fmaf_rn(P[5], p1, c1); c1 = __fmaf_rn(P[6],  p2, c1); c1 = __fmaf_rn(P[7],  1.0f, c1);
    float c2 = __fmul_rn(P[8], p0); c2 = __fmaf_rn(P[9], p1, c2); c2 = __fmaf_rn(P[10], p2, c2); c2 = __fmaf_rn(P[11], 1.0f, c2);
    float denom = __fadd_rn(c2, EPSF);
    float gx = c0 / denom;   // IEEE div — mask-critical, keep exact
    float gy = c1 / denom;

    bool interior = (x >= 2) && (x <= W_ - 3) && (y >= 2) && (y <= H_ - 3);
    bool m = valid && interior && (gx >= 2.0f) && (gx <= (float)(W_ - 2))
                               && (gy >= 2.0f) && (gy <= (float)(H_ - 2));
    float2 g = m ? make_float2(gx, gy) : make_float2(2.0f, -1.0f);
    ((float2*)(ws + GXY_OFF))[tid] = g;
}

// ---------------------------------------------------------------------------
// Kernel 2: sampling. Block = 8 px * 16 lanes (4 ch each); each block walks a
// DCH-deep d-chunk serially (amortizes cv/base setup, keeps ILP).
__global__ __launch_bounds__(128) void sample_kernel(
        const float* __restrict__ ws, float* __restrict__ out) {
    int t    = threadIdx.x;
    int lane = t & 15;
    int px   = t >> 4;                 // 0..7
    int bid  = blockIdx.x;
    int xt  = bid % 13;  int r = bid / 13;
    int d0c = r % (D_ / DCH);  r /= (D_ / DCH);
    int y   = r % H_;
    int b   = r / H_;
    int d0  = d0c * DCH;
    int x   = xt * 8 + px;

    if (y < 2 || y >= H_ - 2) {
        // whole row masked -> cost = 0 everywhere in this block's range
        if (t < 8 * DCH) {
            int dd = t >> 3, p2 = t & 7;
            out[((size_t)(b * D_ + d0 + dd) * H_ + y) * W_ + xt * 8 + p2] = 0.0f;
        }
        return;
    }

    const float* lfT  = ws + LFT_OFF;
    const float* curT = ws + CURT_OFF;
    const float2* gxy = (const float2*)(ws + GXY_OFF);

    const float4 cv = *(const float4*)(curT + ((size_t)(b * H_ + y) * W_ + x) * C_ + lane * 4);
    size_t g0[F_];
    const float* lfb[F_];
    #pragma unroll
    for (int f = 0; f < F_; ++f) {
        g0[f]  = (((size_t)(b * F_ + f) * D_ + d0) * H_ + y) * W_ + x;
        lfb[f] = lfT + (size_t)(b * F_ + f) * HW_ * C_ + lane * 4;
    }

    #pragma unroll 2
    for (int dc = 0; dc < DCH; ++dc) {
        float costsum = 0.f, counts = 0.f;
        #pragma unroll
        for (int f = 0; f < F_; ++f) {
            float2 g = gxy[g0[f] + (size_t)dc * HW_];
            bool  m  = (g.y >= 0.f);
            float gyv = m ? g.y : 2.0f;   // sentinel-safe coords
            float gxv = g.x;
            float x0f = floorf(gxv), y0f = floorf(gyv);
            int   x0  = (int)x0f,    y0  = (int)y0f;
            float wx1 = gxv - x0f, wy1 = gyv - y0f;
            float wx0 = 1.f - wx1, wy0 = 1.f - wy1;
            float w00 = wy0 * wx0, w01 = wy0 * wx1, w10 = wy1 * wx0, w11 = wy1 * wx1;
            const float* bp = lfb[f] + ((size_t)y0 * W_ + x0) * C_;
            float4 v00 = *(const float4*)(bp);
            float4 v01 = *(const float4*)(bp + C_);
            float4 v10 = *(const float4*)(bp + (size_t)W_ * C_);
            float4 v11 = *(const float4*)(bp + (size_t)W_ * C_ + C_);
            float s;
            s  = fabsf(v00.x*w00 + v01.x*w01 + v10.x*w10 + v11.x*w11 - cv.x);
            s += fabsf(v00.y*w00 + v01.y*w01 + v10.y*w10 + v11.y*w11 - cv.y);
            s += fabsf(v00.z*w00 + v01.z*w01 + v10.z*w10 + v11.z*w11 - cv.z);
            s += fabsf(v00.w*w00 + v01.w*w01 + v10.w*w10 + v11.w*w11 - cv.w);
            s += __shfl_xor(s, 1);
            s += __shfl_xor(s, 2);
            s += __shfl_xor(s, 4);
            s += __shfl_xor(s, 8);
            float fm = m ? 1.0f : 0.0f;
            float diff = __fmul_rn(s, 1.0f / 64.0f) * fm;   // same op order as R1
            costsum += diff;
            counts  += (diff > 0.f) ? 1.0f : 0.0f;
        }
        float cost = costsum / __fadd_rn(counts, EPSF);
        if (lane == 0)
            out[((size_t)(b * D_ + d0 + dc) * H_ + y) * W_ + x] = cost;
    }
}

// ---------------------------------------------------------------------------
// Kernel 3: missing-fill. Block = 8 columns x 16 d-lanes; 832 blocks.
__global__ __launch_bounds__(128) void fix_kernel(float* __restrict__ out) {
    int t  = threadIdx.x;
    int px = t & 7, j = t >> 3;            // j in [0,16)
    int colg = blockIdx.x * 8 + px;        // [0, B*HW)  (8 | HW -> no b straddle)
    int b  = colg / HW_;
    int yx = colg % HW_;
    float* base = out + (size_t)b * D_ * HW_ + yx;
    float v[6];
    float pm = 0.f;
    #pragma unroll
    for (int k = 0; k < 6; ++k) {
        v[k] = base[(size_t)(j + 16 * k) * HW_];
        pm = fmaxf(pm, v[k]);
    }
    __shared__ float pmbuf[128];
    __shared__ float cmaxbuf[8];
    pmbuf[t] = pm;
    __syncthreads();
    if (t < 8) {
        float cm = 0.f;
        #pragma unroll
        for (int jj = 0; jj < 16; ++jj) cm = fmaxf(cm, pmbuf[jj * 8 + t]);
        cmaxbuf[t] = cm;
    }
    __syncthreads();
    float cm = cmaxbuf[px];
    #pragma unroll
    for (int k = 0; k < 6; ++k)
        base[(size_t)(j + 16 * k) * HW_] = (v[k] == 0.0f) ? cm : v[k];
}

// ---------------------------------------------------------------------------
extern "C" void kernel_launch(void* const* d_in, const int* in_sizes, int n_in,
                              void* d_out, int out_size, void* d_ws, size_t ws_size,
                              hipStream_t stream) {
    const float* cur        = (const float*)d_in[0];  // [B,C,H,W]
    const float* lf         = (const float*)d_in[1];  // [B,F,C,H,W]
    const float* poses      = (const float*)d_in[2];  // [B,F,4,4]
    const float* K          = (const float*)d_in[3];  // [B,4,4]
    const float* invK       = (const float*)d_in[4];  // [B,4,4]
    const float* depth_bins = (const float*)d_in[5];  // [D]
    float* out = (float*)d_out;
    float* ws  = (float*)d_ws;

    prep_fused<<<NT_BLKS + PROJ_BLKS, 256, 0, stream>>>(cur, lf, poses, K, invK, depth_bins, ws);

    int sample_blocks = B_ * H_ * 13 * (D_ / DCH);   // 9984
    sample_kernel<<<sample_blocks, 128, 0, stream>>>(ws, out);

    fix_kernel<<<(B_ * HW_) / 8, 128, 0, stream>>>(out);
}

// Round 3
// 113.420 us; speedup vs baseline: 1.5585x; 1.1111x over previous
//
#include <hip/hip_runtime.h>
#include <math.h>

// Problem constants: B,F,C,H,W,D
constexpr int B_ = 2, F_ = 2, C_ = 64, H_ = 32, W_ = 104, D_ = 96;
constexpr int HW_ = H_ * W_;             // 3328
#define EPSF 1e-7f

// Workspace layout (floats):
//   lfT  [B,F,H,W,C]   channel-last lookup feats
//   curT [B,H,W,C]     channel-last current feats
constexpr size_t LFT_OFF  = 0;
constexpr size_t CURT_OFF = LFT_OFF + (size_t)B_ * F_ * HW_ * C_;   // 851968
// total ws floats = 1,277,952 (~5.1 MB)

constexpr int NT_BLKS = (HW_ / 32) * (C_ / 32) * (B_ * F_ + B_);  // 1248
constexpr int DCH = 8;   // depths per sampling block

// ---------------------------------------------------------------------------
// Prep: channel-last transpose [C, HW] -> [HW, C] for 6 slices (4 lf + 2 cur).
__global__ __launch_bounds__(256) void prep_kernel(
        const float* __restrict__ cur, const float* __restrict__ lf,
        float* __restrict__ ws) {
    __shared__ float tile[32][33];
    int bid = blockIdx.x;
    int slice = bid / 208;            // 208 = 104 n-blocks * 2 c-blocks
    int rem   = bid % 208;
    int nb = rem % 104, cb = rem / 104;
    const float* inS;
    float* outS;
    if (slice < B_ * F_) {
        inS  = lf + (size_t)slice * C_ * HW_;
        outS = ws + LFT_OFF + (size_t)slice * HW_ * C_;
    } else {
        int s2 = slice - B_ * F_;
        inS  = cur + (size_t)s2 * C_ * HW_;
        outS = ws + CURT_OFF + (size_t)s2 * HW_ * C_;
    }
    int t = threadIdx.x;
    int tx = t & 31, ty = t >> 5;
    int n0 = nb * 32, c0 = cb * 32;
    #pragma unroll
    for (int k = 0; k < 32; k += 8)
        tile[ty + k][tx] = inS[(size_t)(c0 + ty + k) * HW_ + n0 + tx];
    __syncthreads();
    #pragma unroll
    for (int k = 0; k < 32; k += 8)
        outS[(size_t)(n0 + ty + k) * C_ + c0 + tx] = tile[tx][ty + k];
}

// ---------------------------------------------------------------------------
// Fused sample kernel. Block = 128 threads covering 8 px, DCH depths, F frames.
// Phase A: each thread computes ONE (f,dc,px) projection -> LDS (float2).
// Phase B: 16 lanes per px (4 ch each) walk DCH depths; coords from LDS.
__global__ __launch_bounds__(128) void sample_kernel(
        const float* __restrict__ poses, const float* __restrict__ K,
        const float* __restrict__ invK, const float* __restrict__ depth_bins,
        const float* __restrict__ ws, float* __restrict__ out) {
    int t   = threadIdx.x;
    int bid = blockIdx.x;
    int xt  = bid % 13;  int r = bid / 13;
    int d0c = r % (D_ / DCH);  r /= (D_ / DCH);
    int y   = r % H_;
    int b   = r / H_;
    int d0  = d0c * DCH;

    if (y < 2 || y >= H_ - 2) {
        // whole row masked -> cost = 0 (fix_kernel replaces with col max later)
        if (t < 8 * DCH) {
            int dd = t >> 3, p2 = t & 7;
            out[((size_t)(b * D_ + d0 + dd) * H_ + y) * W_ + xt * 8 + p2] = 0.0f;
        }
        return;   // block-uniform exit (y uniform) — no barrier hazard
    }

    __shared__ float2 gls[F_][DCH][8];

    // ---- Phase A: projection (identical FP op order to R2's prep) ----
    {
        int px = t & 7, dc = (t >> 3) & 7, f = t >> 6;
        int x = xt * 8 + px, d = d0 + dc;
        const float* Kb   = K + (size_t)b * 16;
        const float* pose = poses + (size_t)(b * F_ + f) * 16;
        float P[12];
        #pragma unroll
        for (int i = 0; i < 3; ++i) {
            #pragma unroll
            for (int k = 0; k < 4; ++k) {
                float acc = __fmul_rn(Kb[i*4+0], pose[0*4+k]);
                acc = __fmaf_rn(Kb[i*4+1], pose[1*4+k], acc);
                acc = __fmaf_rn(Kb[i*4+2], pose[2*4+k], acc);
                acc = __fmaf_rn(Kb[i*4+3], pose[3*4+k], acc);
                P[i*4+k] = acc;
            }
        }
        float vs = 0.f;
        #pragma unroll
        for (int j = 0; j < 16; ++j) vs += pose[j];
        bool valid = (vs != 0.f);

        const float* iK = invK + (size_t)b * 16;
        float xf = (float)x, yf = (float)y;
        float cam0 = __fmul_rn(iK[0], xf); cam0 = __fmaf_rn(iK[1], yf, cam0); cam0 = __fmaf_rn(iK[2],  1.0f, cam0);
        float cam1 = __fmul_rn(iK[4], xf); cam1 = __fmaf_rn(iK[5], yf, cam1); cam1 = __fmaf_rn(iK[6],  1.0f, cam1);
        float cam2 = __fmul_rn(iK[8], xf); cam2 = __fmaf_rn(iK[9], yf, cam2); cam2 = __fmaf_rn(iK[10], 1.0f, cam2);
        float depth = depth_bins[d];
        float p0 = __fmul_rn(depth, cam0);
        float p1 = __fmul_rn(depth, cam1);
        float p2 = __fmul_rn(depth, cam2);

        float c0 = __fmul_rn(P[0], p0); c0 = __fmaf_rn(P[1], p1, c0); c0 = __fmaf_rn(P[2],  p2, c0); c0 = __fmaf_rn(P[3],  1.0f, c0);
        float c1 = __fmul_rn(P[4], p0); c1 = __fmaf_rn(P[5], p1, c1); c1 = __fmaf_rn(P[6],  p2, c1); c1 = __fmaf_rn(P[7],  1.0f, c1);
        float c2 = __fmul_rn(P[8], p0); c2 = __fmaf_rn(P[9], p1, c2); c2 = __fmaf_rn(P[10], p2, c2); c2 = __fmaf_rn(P[11], 1.0f, c2);
        float denom = __fadd_rn(c2, EPSF);
        float gx = c0 / denom;   // IEEE div — mask-critical
        float gy = c1 / denom;

        bool interior = (x >= 2) && (x <= W_ - 3);   // y already interior
        bool m = valid && interior && (gx >= 2.0f) && (gx <= (float)(W_ - 2))
                                   && (gy >= 2.0f) && (gy <= (float)(H_ - 2));
        gls[f][dc][px] = m ? make_float2(gx, gy) : make_float2(2.0f, -1.0f);
    }
    __syncthreads();

    // ---- Phase B: bilinear sampling + L1 diff + channel reduce ----
    int lane = t & 15, px = t >> 4;
    int x = xt * 8 + px;
    const float4 cv = *(const float4*)(ws + CURT_OFF
                        + ((size_t)((b * H_ + y) * W_ + x)) * C_ + lane * 4);
    const float* lf0 = ws + LFT_OFF + (size_t)(b * F_ + 0) * HW_ * C_ + lane * 4;
    const float* lf1 = ws + LFT_OFF + (size_t)(b * F_ + 1) * HW_ * C_ + lane * 4;

    #pragma unroll 4
    for (int dc = 0; dc < DCH; ++dc) {
        float costsum = 0.f, counts = 0.f;
        #pragma unroll
        for (int f = 0; f < F_; ++f) {
            float2 g = gls[f][dc][px];     // LDS broadcast (16 lanes same addr)
            bool  m  = (g.y >= 0.f);
            float gyv = m ? g.y : 2.0f;    // sentinel-safe coords
            float gxv = g.x;
            float x0f = floorf(gxv), y0f = floorf(gyv);
            int   x0  = (int)x0f,    y0  = (int)y0f;
            float wx1 = gxv - x0f, wy1 = gyv - y0f;
            float wx0 = 1.f - wx1, wy0 = 1.f - wy1;
            float w00 = wy0 * wx0, w01 = wy0 * wx1, w10 = wy1 * wx0, w11 = wy1 * wx1;
            const float* bp = (f == 0 ? lf0 : lf1) + (size_t)(y0 * W_ + x0) * C_;
            float4 v00 = *(const float4*)(bp);
            float4 v01 = *(const float4*)(bp + C_);
            float4 v10 = *(const float4*)(bp + W_ * C_);
            float4 v11 = *(const float4*)(bp + W_ * C_ + C_);
            float s;
            s  = fabsf(v00.x*w00 + v01.x*w01 + v10.x*w10 + v11.x*w11 - cv.x);
            s += fabsf(v00.y*w00 + v01.y*w01 + v10.y*w10 + v11.y*w11 - cv.y);
            s += fabsf(v00.z*w00 + v01.z*w01 + v10.z*w10 + v11.z*w11 - cv.z);
            s += fabsf(v00.w*w00 + v01.w*w01 + v10.w*w10 + v11.w*w11 - cv.w);
            s += __shfl_xor(s, 1);
            s += __shfl_xor(s, 2);
            s += __shfl_xor(s, 4);
            s += __shfl_xor(s, 8);
            float diff = __fmul_rn(s, 1.0f / 64.0f) * (m ? 1.0f : 0.0f);
            costsum += diff;
            counts  += (diff > 0.f) ? 1.0f : 0.0f;
        }
        float cost = costsum / __fadd_rn(counts, EPSF);
        if (lane == 0)
            out[((size_t)(b * D_ + d0 + dc) * H_ + y) * W_ + x] = cost;
    }
}

// ---------------------------------------------------------------------------
// Missing-fill. Block = 8 columns x 16 d-lanes; 832 blocks.
__global__ __launch_bounds__(128) void fix_kernel(float* __restrict__ out) {
    int t  = threadIdx.x;
    int px = t & 7, j = t >> 3;            // j in [0,16)
    int colg = blockIdx.x * 8 + px;        // [0, B*HW)
    int b  = colg / HW_;
    int yx = colg % HW_;
    float* base = out + (size_t)b * D_ * HW_ + yx;
    float v[6];
    float pm = 0.f;
    #pragma unroll
    for (int k = 0; k < 6; ++k) {
        v[k] = base[(size_t)(j + 16 * k) * HW_];
        pm = fmaxf(pm, v[k]);
    }
    __shared__ float pmbuf[128];
    __shared__ float cmaxbuf[8];
    pmbuf[t] = pm;
    __syncthreads();
    if (t < 8) {
        float cm = 0.f;
        #pragma unroll
        for (int jj = 0; jj < 16; ++jj) cm = fmaxf(cm, pmbuf[jj * 8 + t]);
        cmaxbuf[t] = cm;
    }
    __syncthreads();
    float cm = cmaxbuf[px];
    #pragma unroll
    for (int k = 0; k < 6; ++k)
        base[(size_t)(j + 16 * k) * HW_] = (v[k] == 0.0f) ? cm : v[k];
}

// ---------------------------------------------------------------------------
extern "C" void kernel_launch(void* const* d_in, const int* in_sizes, int n_in,
                              void* d_out, int out_size, void* d_ws, size_t ws_size,
                              hipStream_t stream) {
    const float* cur        = (const float*)d_in[0];  // [B,C,H,W]
    const float* lf         = (const float*)d_in[1];  // [B,F,C,H,W]
    const float* poses      = (const float*)d_in[2];  // [B,F,4,4]
    const float* K          = (const float*)d_in[3];  // [B,4,4]
    const float* invK       = (const float*)d_in[4];  // [B,4,4]
    const float* depth_bins = (const float*)d_in[5];  // [D]
    float* out = (float*)d_out;
    float* ws  = (float*)d_ws;

    prep_kernel<<<NT_BLKS, 256, 0, stream>>>(cur, lf, ws);

    int sample_blocks = B_ * H_ * 13 * (D_ / DCH);   // 9984
    sample_kernel<<<sample_blocks, 128, 0, stream>>>(poses, K, invK, depth_bins, ws, out);

    fix_kernel<<<(B_ * HW_) / 8, 128, 0, stream>>>(out);
}

// Round 5
// 109.811 us; speedup vs baseline: 1.6098x; 1.0329x over previous
//
#include <hip/hip_runtime.h>
#include <math.h>

// Problem constants: B,F,C,H,W,D
constexpr int B_ = 2, F_ = 2, C_ = 64, H_ = 32, W_ = 104, D_ = 96;
constexpr int HW_ = H_ * W_;             // 3328
#define EPSF 1e-7f

// Workspace layout (floats):
//   lfT  [B,F,H,W,C]   channel-last lookup feats
//   curT [B,H,W,C]     channel-last current feats
constexpr size_t LFT_OFF  = 0;
constexpr size_t CURT_OFF = LFT_OFF + (size_t)B_ * F_ * HW_ * C_;   // 851968
// total ws floats = 1,277,952 (~5.1 MB)

constexpr int NT_BLKS = (HW_ / 32) * (C_ / 32) * (B_ * F_ + B_);  // 1248

// ---------------------------------------------------------------------------
// Prep: channel-last transpose [C, HW] -> [HW, C] for 6 slices (4 lf + 2 cur).
__global__ __launch_bounds__(256) void prep_kernel(
        const float* __restrict__ cur, const float* __restrict__ lf,
        float* __restrict__ ws) {
    __shared__ float tile[32][33];
    int bid = blockIdx.x;
    int slice = bid / 208;            // 208 = 104 n-blocks * 2 c-blocks
    int rem   = bid % 208;
    int nb = rem % 104, cb = rem / 104;
    const float* inS;
    float* outS;
    if (slice < B_ * F_) {
        inS  = lf + (size_t)slice * C_ * HW_;
        outS = ws + LFT_OFF + (size_t)slice * HW_ * C_;
    } else {
        int s2 = slice - B_ * F_;
        inS  = cur + (size_t)s2 * C_ * HW_;
        outS = ws + CURT_OFF + (size_t)s2 * HW_ * C_;
    }
    int t = threadIdx.x;
    int tx = t & 31, ty = t >> 5;
    int n0 = nb * 32, c0 = cb * 32;
    #pragma unroll
    for (int k = 0; k < 32; k += 8)
        tile[ty + k][tx] = inS[(size_t)(c0 + ty + k) * HW_ + n0 + tx];
    __syncthreads();
    #pragma unroll
    for (int k = 0; k < 32; k += 8)
        outS[(size_t)(n0 + ty + k) * C_ + c0 + tx] = tile[tx][ty + k];
}

// ---------------------------------------------------------------------------
// Mega kernel: block = (b, y, xt) covering 8 px * ALL 96 depths * 2 frames.
// Phase A: 1536 projections -> LDS {texel offset, 4 weights}; masked ->
//          off=-1 AND zero weights (NaN-safe: 0*NaN poison was R4's bug).
// Phase B: two 128-thread halves each walk 48 consecutive depths; 16 lanes/px
//          (4 ch each); corner float4s cached in VGPRs keyed on offset.
// Phase C: in-block missing-fill (cost==0 -> column max) + store.
__global__ __launch_bounds__(256) void mega_kernel(
        const float* __restrict__ poses, const float* __restrict__ K,
        const float* __restrict__ invK, const float* __restrict__ depth_bins,
        const float* __restrict__ ws, float* __restrict__ out) {
    int t   = threadIdx.x;
    int bid = blockIdx.x;
    int xt  = bid % 13;  int r = bid / 13;
    int y   = r % H_;
    int b   = r / H_;

    if (y < 2 || y >= H_ - 2) {
        // whole row masked: cost column all-zero -> column max 0 -> output 0
        for (int k = t; k < 8 * D_; k += 256) {
            int d = k >> 3, px = k & 7;
            out[((size_t)(b * D_ + d) * H_ + y) * W_ + xt * 8 + px] = 0.0f;
        }
        return;   // block-uniform exit
    }

    __shared__ int   offs[F_][D_][8];
    __shared__ float wts [F_][D_][8][4];
    __shared__ float costb[8][D_];
    __shared__ float pmax[32][8];
    __shared__ float cmaxb[8];

    // ---- Phase A: projections (FP op order identical to R3) ----
    #pragma unroll
    for (int f = 0; f < F_; ++f) {
        const float* Kb   = K + (size_t)b * 16;
        const float* pose = poses + (size_t)(b * F_ + f) * 16;
        float P[12];
        #pragma unroll
        for (int i = 0; i < 3; ++i) {
            #pragma unroll
            for (int k = 0; k < 4; ++k) {
                float acc = __fmul_rn(Kb[i*4+0], pose[0*4+k]);
                acc = __fmaf_rn(Kb[i*4+1], pose[1*4+k], acc);
                acc = __fmaf_rn(Kb[i*4+2], pose[2*4+k], acc);
                acc = __fmaf_rn(Kb[i*4+3], pose[3*4+k], acc);
                P[i*4+k] = acc;
            }
        }
        float vs = 0.f;
        #pragma unroll
        for (int j = 0; j < 16; ++j) vs += pose[j];
        bool valid = (vs != 0.f);
        const float* iK = invK + (size_t)b * 16;

        #pragma unroll
        for (int k = 0; k < 3; ++k) {
            int idx = t + 256 * k;          // [0,768) = dd*8 + px
            int dd = idx >> 3, px = idx & 7;
            int x = xt * 8 + px;
            float xf = (float)x, yf = (float)y;
            float cam0 = __fmul_rn(iK[0], xf); cam0 = __fmaf_rn(iK[1], yf, cam0); cam0 = __fmaf_rn(iK[2],  1.0f, cam0);
            float cam1 = __fmul_rn(iK[4], xf); cam1 = __fmaf_rn(iK[5], yf, cam1); cam1 = __fmaf_rn(iK[6],  1.0f, cam1);
            float cam2 = __fmul_rn(iK[8], xf); cam2 = __fmaf_rn(iK[9], yf, cam2); cam2 = __fmaf_rn(iK[10], 1.0f, cam2);
            float depth = depth_bins[dd];
            float p0 = __fmul_rn(depth, cam0);
            float p1 = __fmul_rn(depth, cam1);
            float p2 = __fmul_rn(depth, cam2);
            float c0 = __fmul_rn(P[0], p0); c0 = __fmaf_rn(P[1], p1, c0); c0 = __fmaf_rn(P[2],  p2, c0); c0 = __fmaf_rn(P[3],  1.0f, c0);
            float c1 = __fmul_rn(P[4], p0); c1 = __fmaf_rn(P[5], p1, c1); c1 = __fmaf_rn(P[6],  p2, c1); c1 = __fmaf_rn(P[7],  1.0f, c1);
            float c2 = __fmul_rn(P[8], p0); c2 = __fmaf_rn(P[9], p1, c2); c2 = __fmaf_rn(P[10], p2, c2); c2 = __fmaf_rn(P[11], 1.0f, c2);
            float denom = __fadd_rn(c2, EPSF);
            float gx = c0 / denom;   // IEEE div — mask-critical
            float gy = c1 / denom;
            bool interior = (x >= 2) && (x <= W_ - 3);   // y already interior
            bool m = valid && interior && (gx >= 2.0f) && (gx <= (float)(W_ - 2))
                                       && (gy >= 2.0f) && (gy <= (float)(H_ - 2));
            if (m) {
                float x0f = floorf(gx), y0f = floorf(gy);
                int   x0  = (int)x0f,   y0  = (int)y0f;
                float wx1 = gx - x0f, wy1 = gy - y0f;
                float wx0 = 1.f - wx1, wy0 = 1.f - wy1;
                wts[f][dd][px][0] = wy0 * wx0;
                wts[f][dd][px][1] = wy0 * wx1;
                wts[f][dd][px][2] = wy1 * wx0;
                wts[f][dd][px][3] = wy1 * wx1;
                offs[f][dd][px] = (y0 * W_ + x0) * C_;
            } else {
                offs[f][dd][px] = -1;
                // NaN-safety: weights MUST be finite (diff = s*0; 0*NaN=NaN).
                wts[f][dd][px][0] = 0.f;
                wts[f][dd][px][1] = 0.f;
                wts[f][dd][px][2] = 0.f;
                wts[f][dd][px][3] = 0.f;
            }
        }
    }
    __syncthreads();

    // ---- Phase B: sampling with VGPR corner cache ----
    {
        int lane = t & 15, px = (t >> 4) & 7, half = t >> 7;
        int x = xt * 8 + px;
        const float4 cv = *(const float4*)(ws + CURT_OFF
                            + ((size_t)((b * H_ + y) * W_ + x)) * C_ + lane * 4);
        const float* lfb[F_];
        lfb[0] = ws + LFT_OFF + (size_t)(b * F_ + 0) * HW_ * C_ + lane * 4;
        lfb[1] = ws + LFT_OFF + (size_t)(b * F_ + 1) * HW_ * C_ + lane * 4;

        float4 cc[F_][4];
        int oprev[F_] = { -1, -1 };
        #pragma unroll
        for (int f = 0; f < F_; ++f)
            cc[f][0] = cc[f][1] = cc[f][2] = cc[f][3] = make_float4(0.f, 0.f, 0.f, 0.f);

        int dbeg = half * (D_ / 2), dend = dbeg + (D_ / 2);
        for (int dc = dbeg; dc < dend; ++dc) {
            float costsum = 0.f, counts = 0.f;
            #pragma unroll
            for (int f = 0; f < F_; ++f) {
                int  o = offs[f][dc][px];     // LDS broadcast, group-uniform
                bool m = (o >= 0);
                if (m && o != oprev[f]) {     // group-uniform branch
                    const float* bp = lfb[f] + o;
                    cc[f][0] = *(const float4*)(bp);
                    cc[f][1] = *(const float4*)(bp + C_);
                    cc[f][2] = *(const float4*)(bp + W_ * C_);
                    cc[f][3] = *(const float4*)(bp + W_ * C_ + C_);
                    oprev[f] = o;
                }
                float w00 = wts[f][dc][px][0];
                float w01 = wts[f][dc][px][1];
                float w10 = wts[f][dc][px][2];
                float w11 = wts[f][dc][px][3];
                float s;
                s  = fabsf(cc[f][0].x*w00 + cc[f][1].x*w01 + cc[f][2].x*w10 + cc[f][3].x*w11 - cv.x);
                s += fabsf(cc[f][0].y*w00 + cc[f][1].y*w01 + cc[f][2].y*w10 + cc[f][3].y*w11 - cv.y);
                s += fabsf(cc[f][0].z*w00 + cc[f][1].z*w01 + cc[f][2].z*w10 + cc[f][3].z*w11 - cv.z);
                s += fabsf(cc[f][0].w*w00 + cc[f][1].w*w01 + cc[f][2].w*w10 + cc[f][3].w*w11 - cv.w);
                s += __shfl_xor(s, 1);
                s += __shfl_xor(s, 2);
                s += __shfl_xor(s, 4);
                s += __shfl_xor(s, 8);
                float diff = __fmul_rn(s, 1.0f / 64.0f) * (m ? 1.0f : 0.0f);
                costsum += diff;
                counts  += (diff > 0.f) ? 1.0f : 0.0f;
            }
            float cost = costsum / __fadd_rn(counts, EPSF);
            if (lane == 0) costb[px][dc] = cost;
        }
    }
    __syncthreads();

    // ---- Phase C: missing-fill + store ----
    {
        int j = t >> 3, px = t & 7;          // j in [0,32)
        float v[3];
        float pm = 0.f;
        #pragma unroll
        for (int k = 0; k < 3; ++k) {
            v[k] = costb[px][j + 32 * k];
            pm = fmaxf(pm, v[k]);
        }
        pmax[j][px] = pm;
        __syncthreads();
        if (t < 8) {
            float cm = 0.f;
            #pragma unroll
            for (int jj = 0; jj < 32; ++jj) cm = fmaxf(cm, pmax[jj][t]);
            cmaxb[t] = cm;
        }
        __syncthreads();
        float cm = cmaxb[px];
        int x = xt * 8 + px;
        #pragma unroll
        for (int k = 0; k < 3; ++k) {
            int d = j + 32 * k;
            out[((size_t)(b * D_ + d) * H_ + y) * W_ + x] = (v[k] == 0.0f) ? cm : v[k];
        }
    }
}

// ---------------------------------------------------------------------------
extern "C" void kernel_launch(void* const* d_in, const int* in_sizes, int n_in,
                              void* d_out, int out_size, void* d_ws, size_t ws_size,
                              hipStream_t stream) {
    const float* cur        = (const float*)d_in[0];  // [B,C,H,W]
    const float* lf         = (const float*)d_in[1];  // [B,F,C,H,W]
    const float* poses      = (const float*)d_in[2];  // [B,F,4,4]
    const float* K          = (const float*)d_in[3];  // [B,4,4]
    const float* invK       = (const float*)d_in[4];  // [B,4,4]
    const float* depth_bins = (const float*)d_in[5];  // [D]
    float* out = (float*)d_out;
    float* ws  = (float*)d_ws;

    prep_kernel<<<NT_BLKS, 256, 0, stream>>>(cur, lf, ws);
    mega_kernel<<<B_ * H_ * 13, 256, 0, stream>>>(poses, K, invK, depth_bins, ws, out);
}